// Round 8
// baseline (233.403 us; speedup 1.0000x reference)
//
#include <hip/hip_runtime.h>
#include <stdint.h>

typedef __bf16 bf16;
typedef __attribute__((ext_vector_type(4))) __bf16 bf16x4;
typedef __attribute__((ext_vector_type(8))) __bf16 bf16x8;
typedef __attribute__((ext_vector_type(4))) float f32x4;

#define W_ 160
#define H_ 96
#define C_ 128
#define B_ 16
#define HW_ (H_ * W_)            // 15360
#define NYB 12                   // 96/8
#define NXT 10                   // 160/16
#define NBLK (B_ * NYB * NXT)    // 1920 = 8 * 240
#define WSSTR 1312               // floats; per-wave epilogue transpose region
#define T2BYTES ((size_t)B_ * HW_ * C_ * 2)   // 62,914,560 B

// ================= pass 1: in2 [B][C][H][W] f32 -> ws [B][H][W][C] bf16 (x1/128) =================
__global__ __launch_bounds__(256) void t2_kernel(const float* __restrict__ in2,
                                                 bf16* __restrict__ o) {
    __shared__ __align__(16) bf16 T[W_ * C_];       // 40960 B, one (b,y) row-strip
    const int L   = blockIdx.x;                     // b*H_ + y
    const int tid = threadIdx.x;
    const float* src = in2 + (size_t)(L / H_) * C_ * HW_ + (size_t)(L % H_) * W_;
    bf16* dst = o + (size_t)L * (W_ * C_);
    const float SC = 1.0f / 128.0f;                 // exact fold of 1/(K*K*C)
#pragma unroll
    for (int rd = 0; rd < 5; ++rd) {
        const int s  = rd * 256 + tid;              // 0..1279 = 32 cq x 40 x4
        const int cq = s / 40;
        const int x4 = s - cq * 40;
        const float* p = src + (size_t)(4 * cq) * HW_ + 4 * x4;
        const float4 v0 = *(const float4*)(p);
        const float4 v1 = *(const float4*)(p + HW_);
        const float4 v2 = *(const float4*)(p + 2 * HW_);
        const float4 v3 = *(const float4*)(p + 3 * HW_);
        const int oq = cq >> 1, half = cq & 1;
#pragma unroll
        for (int xj = 0; xj < 4; ++xj) {
            const int x   = 4 * x4 + xj;
            const int pos = oq ^ ((x >> 2) & 15);   // 16B-granular XOR swizzle
            bf16x4 pk;
            pk[0] = (bf16)(((const float*)&v0)[xj] * SC);
            pk[1] = (bf16)(((const float*)&v1)[xj] * SC);
            pk[2] = (bf16)(((const float*)&v2)[xj] * SC);
            pk[3] = (bf16)(((const float*)&v3)[xj] * SC);
            *(bf16x4*)((char*)T + x * 256 + pos * 16 + half * 8) = pk;
        }
    }
    __syncthreads();
#pragma unroll
    for (int wr = 0; wr < 10; ++wr) {
        const int s = wr * 256 + tid;               // 0..2559; byte s*16 = x*256 + oo*16
        const int x = s >> 4, oo = s & 15;
        const bf16x8 vv =
            *(const bf16x8*)((const char*)T + x * 256 + ((oo ^ ((x >> 2) & 15)) * 16));
        *(bf16x8*)((char*)dst + (size_t)s * 16) = vv;   // contiguous 4KB per wave
    }
}

// ================= pass 2: barrier-free MFMA, B direct from in2t =================
__global__ __launch_bounds__(512, 3) void corr_mfma2(const float* __restrict__ in1,
                                                     const bf16* __restrict__ in2t,
                                                     float* __restrict__ out) {
    __shared__ __align__(16) float wsx[8 * WSSTR];  // 41984 B, epilogue only

    const int L   = ((int)blockIdx.x & 7) * (NBLK / 8) + ((int)blockIdx.x >> 3);
    const int b   = L / (NYB * NXT);
    const int rem = L % (NYB * NXT);
    const int yb  = rem / NXT;
    const int xt  = rem % NXT;
    const int x0  = xt * 16, y0 = yb * 8;

    const int tid  = threadIdx.x;
    const int w    = __builtin_amdgcn_readfirstlane(tid >> 6);  // wave 0..7 -> y row
    const int lane = tid & 63;
    const int n    = lane & 15;          // frag col (A row m / B col)
    const int g    = lane >> 4;          // k-octet
    const int y    = y0 + w;

    // ---- A fragments: f32 gather (line-perfect: 16 consecutive x = one 64B line) ----
    const float* abase = in1 + (size_t)b * C_ * HW_ + (size_t)y * W_ + (x0 + n);
    float a_raw[32];
#pragma unroll
    for (int i = 0; i < 32; ++i)
        a_raw[i] = abase[(size_t)((i >> 3) * 32 + g * 8 + (i & 7)) * HW_];
    bf16x8 afrag[4];
#pragma unroll
    for (int ck = 0; ck < 4; ++ck)
#pragma unroll
        for (int j = 0; j < 8; ++j)
            afrag[ck][j] = (bf16)a_raw[ck * 8 + j];

    // ---- B per-lane voffsets (clamped; OOB masked at epilogue) ----
    const char* i2tb = (const char*)in2t + (size_t)b * HW_ * 256;
    int xoff[2]; float xv[2];
#pragma unroll
    for (int t = 0; t < 2; ++t) {
        const int gx = x0 - 4 + n + 16 * t;
        xv[t]   = ((unsigned)gx < (unsigned)W_) ? 1.f : 0.f;
        const int cx = min(max(gx, 0), W_ - 1);
        xoff[t] = cx * 256 + g * 16;
    }

    f32x4 acc[9][2];
#pragma unroll
    for (int dyi = 0; dyi < 9; ++dyi)
#pragma unroll
        for (int t = 0; t < 2; ++t)
            acc[dyi][t] = (f32x4){0.f, 0.f, 0.f, 0.f};

    // ---- main loop: 72 coalesced 1KB wave-loads + 72 MFMAs, no barriers ----
#pragma unroll
    for (int ck = 0; ck < 4; ++ck) {
#pragma unroll
        for (int dyi = 0; dyi < 9; ++dyi) {
            const int gy = y - 4 + dyi;                       // wave-uniform
            const int cy = min(max(gy, 0), H_ - 1);
            const char* rp = i2tb + (size_t)cy * (W_ * 256) + ck * 64;
#pragma unroll
            for (int t = 0; t < 2; ++t) {
                const bf16x8 bfrag = *(const bf16x8*)(rp + xoff[t]);
                acc[dyi][t] = __builtin_amdgcn_mfma_f32_16x16x32_bf16(
                    afrag[ck], bfrag, acc[dyi][t], 0, 0, 0);
            }
        }
    }

    float yv[9];
#pragma unroll
    for (int dyi = 0; dyi < 9; ++dyi)
        yv[dyi] = ((unsigned)(y - 4 + dyi) < (unsigned)H_) ? 1.f : 0.f;

    // ---- epilogue: per-wave LDS transpose -> coalesced stores (r7-verified mapping) ----
    float* wsw = wsx + w * WSSTR;
#pragma unroll
    for (int dyi = 0; dyi < 9; ++dyi)
#pragma unroll
        for (int t = 0; t < 2; ++t)
#pragma unroll
            for (int rr = 0; rr < 4; ++rr) {
                const int m = 4 * g + rr;
                const int d = n + 16 * t - m;
                if ((unsigned)d <= 8u)
                    wsw[(dyi * 9 + d) * 16 + m] = acc[dyi][t][rr] * xv[t] * yv[dyi];
            }
    __syncthreads();

    const int mm = lane & 15, rg = lane >> 4;
    const size_t ob = (size_t)(b * 81) * HW_ + (size_t)y * W_ + (x0 + mm);
#pragma unroll
    for (int q4 = 0; q4 < 20; ++q4) {
        const int rho = q4 * 4 + rg;
        out[ob + (size_t)rho * HW_] = wsw[rho * 16 + mm];
    }
    if (rg == 0)
        out[ob + (size_t)80 * HW_] = wsw[80 * 16 + mm];
}

// ================= fallback (round-7 kernel, used if ws too small) =================
#define XL 24
#define ROWB 16
#define RSTRB (XL * 64)
#define BUFB (ROWB * RSTRB + 2048)

__global__ __launch_bounds__(512, 3) void corr_fb(const float* __restrict__ in1,
                                                  const float* __restrict__ in2,
                                                  float* __restrict__ out) {
    __shared__ __align__(16) char Bsm[2 * BUFB];
    const int L   = ((int)blockIdx.x & 7) * (NBLK / 8) + ((int)blockIdx.x >> 3);
    const int b   = L / (NYB * NXT);
    const int rem = L % (NYB * NXT);
    const int yb  = rem / NXT;
    const int xt  = rem % NXT;
    const int x0  = xt * 16, y0 = yb * 8;
    const int tid  = threadIdx.x;
    const int w    = tid >> 6;
    const int lane = tid & 63;
    const int n    = lane & 15;
    const int g    = lane >> 4;
    const int y    = y0 + w;
    const float* i1b = in1 + (size_t)b * C_ * HW_;
    const float* i2b = in2 + (size_t)b * C_ * HW_;
    const float* abase = i1b + (size_t)y * W_ + (x0 + n);
    float a_raw[32];
#pragma unroll
    for (int ck = 0; ck < 4; ++ck)
#pragma unroll
        for (int j = 0; j < 8; ++j)
            a_raw[ck * 8 + j] = abase[(size_t)(ck * 32 + g * 8 + j) * HW_];
    const bool sact = (tid < 384);
    const int srow = tid / 24;
    const int srem = tid % 24;
    const int sxq  = srem >> 2;
    const int sg   = srem & 3;
    const int gy2  = y0 - 4 + srow;
    const int gx2  = x0 - 4 + 4 * sxq;
    const bool sval = sact && ((unsigned)gy2 < (unsigned)H_) && (gx2 >= 0) && (gx2 + 3 < W_);
    const int cy = min(max(gy2, 0), H_ - 1);
    const int cx = min(max(gx2, 0), W_ - 4);
    const float* sbase = i2b + (size_t)cy * W_ + cx;
    int wb[4];
#pragma unroll
    for (int xi = 0; xi < 4; ++xi) {
        int xl = 4 * sxq + xi;
        int sw = sg ^ ((xl >> 1) & 3);
        wb[xi] = srow * RSTRB + xl * 64 + sw * 16;
    }
    int rb[2];
#pragma unroll
    for (int t = 0; t < 2; ++t) {
        int xl = n + 16 * t;
        int sw = g ^ ((xl >> 1) & 3);
        rb[t] = xl * 64 + sw * 16;
    }
    const float SC = 1.0f / 128.0f;
    const float4 z4 = {0.f, 0.f, 0.f, 0.f};
    float4 sv[8];
#define SLOAD(CK)                                                              \
    {                                                                          \
        _Pragma("unroll")                                                      \
        for (int j8 = 0; j8 < 8; ++j8) {                                       \
            const int c_ = (CK) * 32 + sg * 8 + j8;                            \
            sv[j8] = sval ? *(const float4*)(sbase + (size_t)c_ * HW_) : z4;   \
        }                                                                      \
    }
#define SWRITE(DST)                                                            \
    if (sact) {                                                                \
        _Pragma("unroll")                                                      \
        for (int xi = 0; xi < 4; ++xi) {                                       \
            bf16x8 pk;                                                         \
            _Pragma("unroll")                                                  \
            for (int j8 = 0; j8 < 8; ++j8)                                     \
                pk[j8] = (bf16)(((const float*)&sv[j8])[xi] * SC);             \
            *(bf16x8*)((DST) + wb[xi]) = pk;                                   \
        }                                                                      \
    }
    SLOAD(0);
    SWRITE(Bsm);
    bf16x8 afrag[4];
#pragma unroll
    for (int ck = 0; ck < 4; ++ck)
#pragma unroll
        for (int j = 0; j < 8; ++j)
            afrag[ck][j] = (bf16)a_raw[ck * 8 + j];
    f32x4 acc[9][2];
#pragma unroll
    for (int dyi = 0; dyi < 9; ++dyi)
#pragma unroll
        for (int t = 0; t < 2; ++t)
            acc[dyi][t] = (f32x4){0.f, 0.f, 0.f, 0.f};
    __syncthreads();
#pragma unroll
    for (int ck = 0; ck < 4; ++ck) {
        const char* cbuf = Bsm + (ck & 1) * BUFB;
        if (ck < 3) SLOAD(ck + 1);
#pragma unroll
        for (int dyi = 0; dyi < 9; ++dyi) {
            const int rowoff = (w + dyi) * RSTRB;
#pragma unroll
            for (int t = 0; t < 2; ++t) {
                bf16x8 bfrag = *(const bf16x8*)(cbuf + rowoff + rb[t]);
                acc[dyi][t] = __builtin_amdgcn_mfma_f32_16x16x32_bf16(
                    afrag[ck], bfrag, acc[dyi][t], 0, 0, 0);
            }
        }
        if (ck < 3) SWRITE(Bsm + ((ck + 1) & 1) * BUFB);
        __syncthreads();
    }
#undef SLOAD
#undef SWRITE
    float* wsw = (float*)Bsm + w * WSSTR;
#pragma unroll
    for (int dyi = 0; dyi < 9; ++dyi)
#pragma unroll
        for (int t = 0; t < 2; ++t)
#pragma unroll
            for (int rr = 0; rr < 4; ++rr) {
                const int m = 4 * g + rr;
                const int d = n + 16 * t - m;
                if ((unsigned)d <= 8u)
                    wsw[(dyi * 9 + d) * 16 + m] = acc[dyi][t][rr];
            }
    __syncthreads();
    const int mm = lane & 15, rg = lane >> 4;
    const size_t ob = (size_t)(b * 81) * HW_ + (size_t)y * W_ + (x0 + mm);
#pragma unroll
    for (int q4 = 0; q4 < 20; ++q4) {
        const int rho = q4 * 4 + rg;
        out[ob + (size_t)rho * HW_] = wsw[rho * 16 + mm];
    }
    if (rg == 0)
        out[ob + (size_t)80 * HW_] = wsw[80 * 16 + mm];
}

extern "C" void kernel_launch(void* const* d_in, const int* in_sizes, int n_in,
                              void* d_out, int out_size, void* d_ws, size_t ws_size,
                              hipStream_t stream) {
    const float* in1 = (const float*)d_in[0];
    const float* in2 = (const float*)d_in[1];
    float* out = (float*)d_out;
    (void)in_sizes; (void)n_in; (void)out_size;
    if (ws_size >= T2BYTES) {
        bf16* in2t = (bf16*)d_ws;
        hipLaunchKernelGGL(t2_kernel, dim3(B_ * H_), dim3(256), 0, stream, in2, in2t);
        hipLaunchKernelGGL(corr_mfma2, dim3(NBLK), dim3(512), 0, stream, in1, in2t, out);
    } else {
        hipLaunchKernelGGL(corr_fb, dim3(NBLK), dim3(512), 0, stream, in1, in2, out);
    }
}

// Round 10
// 202.343 us; speedup vs baseline: 1.1535x; 1.1535x over previous
//
#include <hip/hip_runtime.h>
#include <stdint.h>

typedef __bf16 bf16;
typedef __attribute__((ext_vector_type(4))) __bf16 bf16x4;
typedef __attribute__((ext_vector_type(8))) __bf16 bf16x8;
typedef __attribute__((ext_vector_type(4))) float f32x4;

#define W_ 160
#define H_ 96
#define C_ 128
#define B_ 16
#define HW_ (H_ * W_)            // 15360
#define NXT 10                   // 160/16
#define NYB2 48                  // 96/2: 2-row y-bands
#define NBLK2 (B_ * NYB2 * NXT)  // 7680 = 8 * 960
#define WSSTR 1312               // floats per wave epilogue region (>= 81*16)

// ============ pass 1: in2 [B][C][H][W] f32 -> ws [B][H][W][C] bf16 (x 1/128) ============
__global__ __launch_bounds__(256) void t2_kernel(const float* __restrict__ in2,
                                                 bf16* __restrict__ o) {
    __shared__ __align__(16) bf16 T[W_ * C_];       // 40960 B, one (b,y) row-strip
    const int L   = blockIdx.x;                     // b*H_ + y
    const int tid = threadIdx.x;
    const float* src = in2 + (size_t)(L / H_) * C_ * HW_ + (size_t)(L % H_) * W_;
    bf16* dst = o + (size_t)L * (W_ * C_);
    const float SC = 1.0f / 128.0f;                 // exact fold of 1/(K*K*C)
#pragma unroll
    for (int rd = 0; rd < 5; ++rd) {
        const int s  = rd * 256 + tid;              // 0..1279 = 32 cq x 40 x4
        const int cq = s / 40;
        const int x4 = s - cq * 40;
        const float* p = src + (size_t)(4 * cq) * HW_ + 4 * x4;
        const float4 v0 = *(const float4*)(p);
        const float4 v1 = *(const float4*)(p + HW_);
        const float4 v2 = *(const float4*)(p + 2 * HW_);
        const float4 v3 = *(const float4*)(p + 3 * HW_);
        const int oq = cq >> 1, half = cq & 1;
#pragma unroll
        for (int xj = 0; xj < 4; ++xj) {
            const int x   = 4 * x4 + xj;
            const int pos = oq ^ ((x >> 2) & 15);   // 16B-granular XOR swizzle
            bf16x4 pk;
            pk[0] = (bf16)(((const float*)&v0)[xj] * SC);
            pk[1] = (bf16)(((const float*)&v1)[xj] * SC);
            pk[2] = (bf16)(((const float*)&v2)[xj] * SC);
            pk[3] = (bf16)(((const float*)&v3)[xj] * SC);
            *(bf16x4*)((char*)T + x * 256 + pos * 16 + half * 8) = pk;
        }
    }
    __syncthreads();
#pragma unroll
    for (int wr = 0; wr < 10; ++wr) {
        const int s = wr * 256 + tid;               // byte s*16 = x*256 + oo*16
        const int x = s >> 4, oo = s & 15;
        const bf16x8 vv =
            *(const bf16x8*)((const char*)T + x * 256 + ((oo ^ ((x >> 2) & 15)) * 16));
        *(bf16x8*)((char*)dst + (size_t)s * 16) = vv;   // contiguous 4KB per wave
    }
}

// ============ pass 2: 4-wave blocks, wave = (y-row, c-half); barrier-free main loop ============
__global__ __launch_bounds__(256, 3) void corr_mfma3(const float* __restrict__ in1,
                                                     const bf16* __restrict__ in2t,
                                                     float* __restrict__ out) {
    __shared__ __align__(16) float wsx[4 * WSSTR];  // 20992 B, epilogue only

    const int L   = ((int)blockIdx.x & 7) * (NBLK2 / 8) + ((int)blockIdx.x >> 3);
    const int b   = L / (NYB2 * NXT);
    const int rem = L % (NYB2 * NXT);
    const int yb  = rem / NXT;
    const int xt  = rem % NXT;
    const int x0  = xt * 16, y0 = yb * 2;

    const int tid  = threadIdx.x;
    const int wv   = __builtin_amdgcn_readfirstlane(tid >> 6);  // 0..3
    const int row  = wv & 1;             // y = y0 + row
    const int half = wv >> 1;            // c-half: c in [64*half, 64*half+64)
    const int lane = tid & 63;
    const int n    = lane & 15;          // frag col (A row m / B col)
    const int g    = lane >> 4;          // k-octet
    const int y    = y0 + row;

    // ---- A fragments for this wave's c-half: 16 scattered f32 loads ----
    const float* abase = in1 + (size_t)b * C_ * HW_ + (size_t)y * W_ + (x0 + n);
    float a_raw[16];
#pragma unroll
    for (int i = 0; i < 16; ++i)
        a_raw[i] = abase[(size_t)(half * 64 + (i >> 3) * 32 + g * 8 + (i & 7)) * HW_];
    bf16x8 afrag[2];
#pragma unroll
    for (int k2 = 0; k2 < 2; ++k2)
#pragma unroll
        for (int j = 0; j < 8; ++j)
            afrag[k2][j] = (bf16)a_raw[k2 * 8 + j];

    // ---- B per-lane voffsets (clamped; OOB masked at epilogue) ----
    const char* i2tb = (const char*)in2t + (size_t)b * HW_ * 256;
    int xoff[2]; float xv[2];
#pragma unroll
    for (int t = 0; t < 2; ++t) {
        const int gx = x0 - 4 + n + 16 * t;
        xv[t]   = ((unsigned)gx < (unsigned)W_) ? 1.f : 0.f;
        const int cx = min(max(gx, 0), W_ - 1);
        xoff[t] = cx * 256 + g * 16;
    }

    f32x4 acc[9][2];
#pragma unroll
    for (int dyi = 0; dyi < 9; ++dyi)
#pragma unroll
        for (int t = 0; t < 2; ++t)
            acc[dyi][t] = (f32x4){0.f, 0.f, 0.f, 0.f};

    // ---- main loop: 36 coalesced wave-loads + 36 MFMAs, no barriers ----
#pragma unroll
    for (int k2 = 0; k2 < 2; ++k2) {
        const int ck = half * 2 + k2;
#pragma unroll
        for (int dyi = 0; dyi < 9; ++dyi) {
            const int gy = y - 4 + dyi;                     // wave-uniform
            const int cy = min(max(gy, 0), H_ - 1);
            const char* rp = i2tb + (size_t)cy * (W_ * 256) + ck * 64;
#pragma unroll
            for (int t = 0; t < 2; ++t) {
                const bf16x8 bfrag = *(const bf16x8*)(rp + xoff[t]);
                acc[dyi][t] = __builtin_amdgcn_mfma_f32_16x16x32_bf16(
                    afrag[k2], bfrag, acc[dyi][t], 0, 0, 0);
            }
        }
    }

    float yv[9];
#pragma unroll
    for (int dyi = 0; dyi < 9; ++dyi)
        yv[dyi] = ((unsigned)(y - 4 + dyi) < (unsigned)H_) ? 1.f : 0.f;

    // ---- epilogue phase 1: masked scatter into this wave's own LDS region ----
    // C/D mapping (r6/r7-verified): acc[dyi][t][rr] = C[m=4g+rr][x' = n+16t]; d = x'-m.
    // Region index IS wv = row + 2*half.
    float* wsr = wsx + wv * WSSTR;
#pragma unroll
    for (int dyi = 0; dyi < 9; ++dyi)
#pragma unroll
        for (int t = 0; t < 2; ++t)
#pragma unroll
            for (int rr = 0; rr < 4; ++rr) {
                const int m = 4 * g + rr;
                const int d = n + 16 * t - m;
                if ((unsigned)d <= 8u)
                    wsr[(dyi * 9 + d) * 16 + m] = acc[dyi][t][rr] * xv[t] * yv[dyi];
            }
    __syncthreads();

    // ---- phase 2: sum the two c-halves OF THIS ROW (regions row and row+2) ----
    const int mm = lane & 15, rg = lane >> 4;
    const float* r0 = wsx + (row + 0) * WSSTR;       // (row, half0) region
    const float* r1 = wsx + (row + 2) * WSSTR;       // (row, half1) region
    const size_t ob = (size_t)(b * 81) * HW_ + (size_t)y * W_ + (x0 + mm);
#pragma unroll
    for (int i = 0; i < 10; ++i) {
        const int q4  = half * 10 + i;
        const int rho = q4 * 4 + rg;
        const int idx = rho * 16 + mm;
        out[ob + (size_t)rho * HW_] = r0[idx] + r1[idx];
    }
    if (half == 0 && rg == 0)
        out[ob + (size_t)80 * HW_] = r0[80 * 16 + mm] + r1[80 * 16 + mm];
}

extern "C" void kernel_launch(void* const* d_in, const int* in_sizes, int n_in,
                              void* d_out, int out_size, void* d_ws, size_t ws_size,
                              hipStream_t stream) {
    const float* in1 = (const float*)d_in[0];
    const float* in2 = (const float*)d_in[1];
    float* out = (float*)d_out;
    (void)in_sizes; (void)n_in; (void)out_size; (void)ws_size;
    bf16* in2t = (bf16*)d_ws;            // 63 MB < ws_size (verified: r8 ran this path)
    hipLaunchKernelGGL(t2_kernel, dim3(B_ * H_), dim3(256), 0, stream, in2, in2t);
    hipLaunchKernelGGL(corr_mfma3, dim3(NBLK2), dim3(256), 0, stream, in1, in2t, out);
}

// Round 11
// 103.626 us; speedup vs baseline: 2.2523x; 1.9526x over previous
//
#include <hip/hip_runtime.h>
#include <stdint.h>

typedef __bf16 bf16;
typedef __attribute__((ext_vector_type(4))) __bf16 bf16x4;
typedef __attribute__((ext_vector_type(8))) __bf16 bf16x8;
typedef __attribute__((ext_vector_type(4))) float f32x4;
typedef __attribute__((ext_vector_type(4))) unsigned int u32x4;

#define W_ 160
#define H_ 96
#define C_ 128
#define B_ 16
#define HW_ (H_ * W_)            // 15360
#define NXT 10                   // 160/16
#define NYB4 24                  // 96/4: 4-row y-bands
#define NBLK (B_ * NYB4 * NXT)   // 3840 = 8*480
#define SLICEB 10240             // in2t bytes per (y,ck) slice: 160x * 4 granules * 16B
#define YB 40960                 // per (b,y): 4 slices
#define ROWSB 2048               // LDS bytes per staged row: 32 xl-slots * 64B
#define CHB (12 * ROWSB)         // 24576 B per chunk (12 halo rows)
#define WSSTR 1312               // floats per wave epilogue region

__device__ float g_zero[16];     // zero-initialized; never written

__device__ __forceinline__ void g2l16(const void* g, void* l) {
    __builtin_amdgcn_global_load_lds(
        (const __attribute__((address_space(1))) void*)g,
        (__attribute__((address_space(3))) void*)l, 16, 0, 0);
}

// ===== pass 1: in2 [B][C][H][W] f32 -> in2t [b][y][ck][x*4+(g^((x>>1)&3))] bf16 granules (x 1/128)
__global__ __launch_bounds__(256) void t2_kernel(const float* __restrict__ in2,
                                                 char* __restrict__ o) {
    __shared__ __align__(16) char T[40960];         // [x][pos-swizzled 16 granules]
    const int L   = blockIdx.x;                     // b*H_ + y
    const int tid = threadIdx.x;
    const float* src = in2 + (size_t)(L / H_) * C_ * HW_ + (size_t)(L % H_) * W_;
    char* dst = o + (size_t)L * YB;
    const float SC = 1.0f / 128.0f;                 // exact fold of 1/(K*K*C)
#pragma unroll
    for (int rd = 0; rd < 5; ++rd) {                // load + c->x transpose (r8-proven)
        const int s  = rd * 256 + tid;              // 0..1279 = 32 cq x 40 x4
        const int cq = s / 40;
        const int x4 = s - cq * 40;
        const float* p = src + (size_t)(4 * cq) * HW_ + 4 * x4;
        const float4 v0 = *(const float4*)(p);
        const float4 v1 = *(const float4*)(p + HW_);
        const float4 v2 = *(const float4*)(p + 2 * HW_);
        const float4 v3 = *(const float4*)(p + 3 * HW_);
        const int oq = cq >> 1, half = cq & 1;
#pragma unroll
        for (int xj = 0; xj < 4; ++xj) {
            const int x   = 4 * x4 + xj;
            const int pos = oq ^ ((x >> 2) & 15);   // T's own bank swizzle
            bf16x4 pk;
            pk[0] = (bf16)(((const float*)&v0)[xj] * SC);
            pk[1] = (bf16)(((const float*)&v1)[xj] * SC);
            pk[2] = (bf16)(((const float*)&v2)[xj] * SC);
            pk[3] = (bf16)(((const float*)&v3)[xj] * SC);
            *(bf16x4*)(T + x * 256 + pos * 16 + half * 8) = pk;
        }
    }
    __syncthreads();
#pragma unroll
    for (int wr = 0; wr < 10; ++wr) {               // write in [ck][x][gsw] granule order
        const int s2  = wr * 256 + tid;             // 0..2559
        const int ck  = s2 / 640;
        const int r   = s2 - ck * 640;
        const int x   = r >> 2;
        const int gsw = r & 3;
        const int gg  = gsw ^ ((x >> 1) & 3);       // octet stored at this granule
        const int oo  = ck * 4 + gg;
        const int pos = oo ^ ((x >> 2) & 15);
        const u32x4 v = *(const u32x4*)(T + x * 256 + pos * 16);
        *(u32x4*)(dst + (size_t)s2 * 16) = v;       // fully coalesced
    }
}

// ===== pass 2: 4-wave block = 4 y-rows; B staged (dbuf) via global_load_lds from in2t
__global__ __launch_bounds__(256, 3) void corr_mfma4(const float* __restrict__ in1,
                                                     const char* __restrict__ in2t,
                                                     float* __restrict__ out) {
    __shared__ __align__(16) char Bsm[2 * CHB];     // 49152 B; reused for epilogue

    const int L   = ((int)blockIdx.x & 7) * (NBLK / 8) + ((int)blockIdx.x >> 3);
    const int b   = L / (NYB4 * NXT);
    const int rem = L % (NYB4 * NXT);
    const int yb  = rem / NXT;
    const int xt  = rem % NXT;
    const int x0  = xt * 16, y0 = yb * 4;

    const int tid  = threadIdx.x;
    const int wv   = __builtin_amdgcn_readfirstlane(tid >> 6);  // wave 0..3 -> y row
    const int lane = tid & 63;
    const int n    = lane & 15;          // frag col (A row m / B col)
    const int g    = lane >> 4;          // k-octet
    const int y    = y0 + wv;

    const char* i2tb = in2t + (size_t)b * (H_ * YB);

    // ---- stage descriptors: 6 rounds x 256 thr = 1536 slots = 12 rows x 128 ----
    const char* srow[6];
    bool stgv[6];
#pragma unroll
    for (int rd = 0; rd < 6; ++rd) {
        const int s   = rd * 256 + tid;
        const int row = s >> 7;                     // 0..11
        const int sl  = s & 127;                    // granule within row (>=96: zero pad)
        const int gy  = y0 - 4 + row;
        const int x   = x0 - 4 + (sl >> 2);
        stgv[rd] = (sl < 96) && ((unsigned)gy < (unsigned)H_) && ((unsigned)x < (unsigned)W_);
        const int gy_c = min(max(gy, 0), H_ - 1);
        const int ofs  = max((x0 - 4) * 64 + sl * 16, 0);
        srow[rd] = i2tb + (size_t)gy_c * YB + ofs;  // + ck*SLICEB at stage time
    }

    // Full-wave exec; invalid lanes pull 16B zeros from g_zero (r3-proven).
    // LDS dest is linear in lane order (m104 rule).
#define STAGE(CK, DST)                                                        \
    {                                                                         \
        _Pragma("unroll")                                                     \
        for (int rd = 0; rd < 6; ++rd)                                        \
            g2l16(stgv[rd] ? (const void*)(srow[rd] + (CK) * SLICEB)          \
                           : (const void*)g_zero,                             \
                  (void*)((DST) + rd * 4096 + tid * 16));                     \
    }

    STAGE(0, Bsm);                       // prologue: chunk 0 -> buf 0 (issued first)

    // ---- A fragments (r8-proven gather; drains with prologue barrier) ----
    const float* abase = in1 + (size_t)b * C_ * HW_ + (size_t)y * W_ + (x0 + n);
    float a_raw[32];
#pragma unroll
    for (int i = 0; i < 32; ++i)
        a_raw[i] = abase[(size_t)((i >> 3) * 32 + g * 8 + (i & 7)) * HW_];
    bf16x8 afrag[4];
#pragma unroll
    for (int ck = 0; ck < 4; ++ck)
#pragma unroll
        for (int j = 0; j < 8; ++j)
            afrag[ck][j] = (bf16)a_raw[ck * 8 + j];

    // ---- B-frag read offsets; swizzle term ((x0-4+xl)>>1)&3 == ((xl+12)>>1)&3 ----
    int rboff[2];
#pragma unroll
    for (int t = 0; t < 2; ++t) {
        const int xl = n + 16 * t;
        const int sw = g ^ (((xl + 12) >> 1) & 3);
        rboff[t] = (xl * 4 + sw) * 16;
    }

    f32x4 acc[9][2];
#pragma unroll
    for (int dyi = 0; dyi < 9; ++dyi)
#pragma unroll
        for (int t = 0; t < 2; ++t)
            acc[dyi][t] = (f32x4){0.f, 0.f, 0.f, 0.f};

    __syncthreads();                     // buf0 staged (vmcnt drained), A in regs

#pragma unroll
    for (int ck = 0; ck < 4; ++ck) {
        const char* cbuf = Bsm + (ck & 1) * CHB;
        if (ck < 3) STAGE(ck + 1, Bsm + ((ck + 1) & 1) * CHB);
#pragma unroll
        for (int dyi = 0; dyi < 9; ++dyi) {
            const int rowoff = (wv + dyi) * ROWSB;  // wave-uniform LDS row
#pragma unroll
            for (int t = 0; t < 2; ++t) {
                const bf16x8 bfrag = *(const bf16x8*)(cbuf + rowoff + rboff[t]);
                acc[dyi][t] = __builtin_amdgcn_mfma_f32_16x16x32_bf16(
                    afrag[ck], bfrag, acc[dyi][t], 0, 0, 0);
            }
        }
        if (ck < 3) __syncthreads();     // next chunk staged; buffer turnover safe
    }
#undef STAGE

    // ---- epilogue (r7-proven): per-wave LDS transpose -> coalesced stores ----
    // Zero-staged padding made all boundary outputs exact 0 -> maskless.
    float* wsw = (float*)Bsm + wv * WSSTR;          // 4*5248 B = 20992 <= CHB (buf0 done)
#pragma unroll
    for (int dyi = 0; dyi < 9; ++dyi)
#pragma unroll
        for (int t = 0; t < 2; ++t)
#pragma unroll
            for (int rr = 0; rr < 4; ++rr) {
                const int m = 4 * g + rr;
                const int d = n + 16 * t - m;
                if ((unsigned)d <= 8u)
                    wsw[(dyi * 9 + d) * 16 + m] = acc[dyi][t][rr];
            }
    __syncthreads();

    const int mm = lane & 15, rg = lane >> 4;
    const size_t ob = (size_t)(b * 81) * HW_ + (size_t)y * W_ + (x0 + mm);
#pragma unroll
    for (int q4 = 0; q4 < 20; ++q4) {
        const int rho = q4 * 4 + rg;
        out[ob + (size_t)rho * HW_] = wsw[rho * 16 + mm];
    }
    if (rg == 0)
        out[ob + (size_t)80 * HW_] = wsw[80 * 16 + mm];
}

extern "C" void kernel_launch(void* const* d_in, const int* in_sizes, int n_in,
                              void* d_out, int out_size, void* d_ws, size_t ws_size,
                              hipStream_t stream) {
    const float* in1 = (const float*)d_in[0];
    const float* in2 = (const float*)d_in[1];
    float* out = (float*)d_out;
    (void)in_sizes; (void)n_in; (void)out_size; (void)ws_size;
    char* in2t = (char*)d_ws;            // 62.9 MB (same as r8's verified-fitting layout)
    hipLaunchKernelGGL(t2_kernel, dim3(B_ * H_), dim3(256), 0, stream, in2, in2t);
    hipLaunchKernelGGL(corr_mfma4, dim3(NBLK), dim3(256), 0, stream, in1, in2t, out);
}